// Round 4
// baseline (245.540 us; speedup 1.0000x reference)
//
#include <hip/hip_runtime.h>
#include <hip/hip_bf16.h>
#include <type_traits>

typedef __attribute__((ext_vector_type(8))) _Float16 half8;
typedef __attribute__((ext_vector_type(4))) _Float16 half4;
typedef __attribute__((ext_vector_type(4))) float f32x4;

constexpr int CB = 48, CS = 128, CW = 4, CK = 256;
constexpr int LDP = 264;  // padded ebuf row stride (halves)

// eT[b][k][kp] = exp(T[b][k][kp] * tag_mask[b][k][kp]) as f16, float4-vectorized
__global__ void prep_eT_kernel(const f32x4* __restrict__ T,
                               const f32x4* __restrict__ tm,
                               half4* __restrict__ eT, int n4) {
    int i = blockIdx.x * 256 + threadIdx.x;
    if (i < n4) {
        f32x4 t = T[i], m = tm[i];
        half4 o;
        o[0] = (_Float16)__expf(t[0] * m[0]);
        o[1] = (_Float16)__expf(t[1] * m[1]);
        o[2] = (_Float16)__expf(t[2] * m[2]);
        o[3] = (_Float16)__expf(t[3] * m[3]);
        eT[i] = o;
    }
}

// 8 waves / 512 threads: wave wv owns k-slice [wv*32, wv*32+32).
// B-fragments: 16 half8 = 64 VGPR/lane, PINNED register-resident (asm pin prevents remat).
// launch_bounds(512,1): only 48 blocks exist; give the allocator the full 256-VGPR budget.
__global__ __launch_bounds__(512, 1)
void crf_scan_kernel(const float* __restrict__ logits,
                     const float* __restrict__ ham,
                     const _Float16* __restrict__ eT,
                     const float* __restrict__ tag_mask,
                     const int* __restrict__ text_mask,
                     float* __restrict__ out) {
    const int b = blockIdx.x;
    const int tid = (int)threadIdx.x;
    const int wv = tid >> 6;
    const int lane = tid & 63;
    const int l16 = lane & 15;
    const int g4 = lane >> 4;
    const int kb = wv * 32;
    const int k0 = kb + l16;        // t=0 column
    const int k1 = kb + 16 + l16;   // t=1 column

    __shared__ alignas(16) _Float16 ebuf[4 * LDP];  // ring: slot of alpha_i = i&3
    __shared__ float red[8];
    __shared__ int len_s;

    if (tid == 0) len_s = 0;
    __syncthreads();
    if (tid < CS) atomicAdd(&len_s, text_mask[b * CS + tid]);
    // alpha_{-1} = zeros row: e = exp(0-0) = 1 in slot 3, M_{-1} = 0
    if (tid < CK) ebuf[3 * LDP + tid] = (_Float16)1.0f;

    const float tm0a = tag_mask[(size_t)b * CK * CK + k0];  // tag_mask[b,0,k]
    const float tm0b = tag_mask[(size_t)b * CK * CK + k1];

    // persistent eT B-fragments: bfr[c][t] for this wave's two 16-wide k tiles
    half8 bfr[8][2];
    const _Float16* eTb = eT + (size_t)b * CK * CK;
#pragma unroll
    for (int c = 0; c < 8; ++c) {
        bfr[c][0] = *(const half8*)(eTb + (size_t)k0 * CK + c * 32 + g4 * 8);
        bfr[c][1] = *(const half8*)(eTb + (size_t)k1 * CK + c * 32 + g4 * 8);
    }
    // pin: make values opaque so the compiler can't re-load them from eT inside the loop
#pragma unroll
    for (int c = 0; c < 8; ++c)
        asm volatile("" : "+v"(bfr[c][0]), "+v"(bfr[c][1]));

    const float* lgb = logits + (size_t)b * CS * CW * CK;
    const float* hcb = ham    + (size_t)b * CS * CW * CK;

    // persistent A-fragments, slot-duplicated rows: A row r holds slot (r&3).
    half8 af[8];
    {
        const _Float16 iv = ((l16 & 3) == 3) ? (_Float16)1.0f : (_Float16)0.0f;
        half8 v;
#pragma unroll
        for (int i = 0; i < 8; ++i) v[i] = iv;
#pragma unroll
        for (int c = 0; c < 8; ++c) af[c] = v;
    }

    // wave-uniform scan state
    float mr[4] = {0.0f, 0.0f, 0.0f, 0.0f};  // mr[s] = normalizer M of alpha in slot s
    float ls_prev = __logf(256.0f) - 2.0f;   // pretend ls_{-1}
    float out_r = __logf(256.0f);            // ls[0] (len==0 case)
    float e_last0 = 0.0f, e_last1 = 0.0f, M_last = 0.0f;
    // deferred normalizer: Mcur/scl for step j are decided at step j-1.
    float Mcur = __logf(256.0f) + 2.0f;      // M_0 = log256 + 2 (matches old seed)
    float scl  = __expf(0.0f - Mcur);        // C_0 = mr[3] = 0

    // 2-deep emission prefetch: set p = j&1; [p][w][t]
    float lgp[2][4][2], hcp[2][4][2];
#pragma unroll
    for (int d = 0; d < 2; ++d)
#pragma unroll
        for (int w = 0; w < 4; ++w) {
            int i0 = d * (CW * CK) + w * CK;
            lgp[d][w][0] = lgb[i0 + k0];
            lgp[d][w][1] = lgb[i0 + k1];
            hcp[d][w][0] = hcb[i0 + k0];
            hcp[d][w][1] = hcb[i0 + k1];
        }

    __syncthreads();
    const int len = len_s;

    half8 ones;
#pragma unroll
    for (int i = 0; i < 8; ++i) ones[i] = (_Float16)1.0f;
    asm volatile("" : "+v"(ones));

    auto step = [&](int j, auto uc, auto firstc) {
        constexpr int u = uc.value;          // j & 3 (slot written this step)
        constexpr bool first = firstc.value; // j < 4 block
        constexpr int sp = (u + 3) & 3;      // slot of alpha_{j-1}
        constexpr int p = u & 1;             // prefetch set

        // masked A-frag update: only row group sp changed since last step.
        if ((l16 & 3) == sp) {
#pragma unroll
            for (int c = 0; c < 8; ++c)
                af[c] = *(const half8*)(ebuf + sp * LDP + c * 32 + g4 * 8);
        }

        // consume prefetch set p (issued 2 steps ago)
        float em[4][2];
#pragma unroll
        for (int w = 0; w < 4; ++w) {
            em[w][0] = (lgp[p][w][0] + hcp[p][w][0]) * tm0a;
            em[w][1] = (lgp[p][w][1] + hcp[p][w][1]) * tm0b;
        }

        // reissue set p for step j+2 (in flight across barriers)
        {
            int jn = (j + 2 < CS) ? j + 2 : 0;  // wave-uniform clamp (dummy ok)
            int i0 = jn * (CW * CK);
#pragma unroll
            for (int w = 0; w < 4; ++w) {
                lgp[p][w][0] = lgb[i0 + w * CK + k0];
                lgp[p][w][1] = lgb[i0 + w * CK + k1];
                hcp[p][w][0] = hcb[i0 + w * CK + k0];
                hcp[p][w][1] = hcb[i0 + w * CK + k1];
            }
        }

        // slot weights need only mr[]/C (known since last step) -> off MFMA path
        const float C = mr[sp];
        float E0[4], E1[4];
#pragma unroll
        for (int r = 0; r < 4; ++r) {
            const int w = (u + 3 - r) & 3;
            E0[r] = __expf(mr[r] + em[w][0] - C);
            E1[r] = __expf(mr[r] + em[w][1] - C);
        }
        mr[u] = Mcur;   // record this step's normalizer (after E read old mr[u])

        // MFMA: y[slot r][k] tiles + all-ones tile for row sums; 4-deep split chains
        f32x4 a0 = {0,0,0,0}, a1 = {0,0,0,0};
        f32x4 b0 = {0,0,0,0}, b1 = {0,0,0,0};
        f32x4 s0 = {0,0,0,0}, s1 = {0,0,0,0};
#pragma unroll
        for (int c = 0; c < 4; ++c) {
            a0 = __builtin_amdgcn_mfma_f32_16x16x32_f16(af[c], bfr[c][0], a0, 0, 0, 0);
            b0 = __builtin_amdgcn_mfma_f32_16x16x32_f16(af[c], bfr[c][1], b0, 0, 0, 0);
            s0 = __builtin_amdgcn_mfma_f32_16x16x32_f16(af[c], ones, s0, 0, 0, 0);
        }
#pragma unroll
        for (int c = 4; c < 8; ++c) {
            a1 = __builtin_amdgcn_mfma_f32_16x16x32_f16(af[c], bfr[c][0], a1, 0, 0, 0);
            b1 = __builtin_amdgcn_mfma_f32_16x16x32_f16(af[c], bfr[c][1], b1, 0, 0, 0);
            s1 = __builtin_amdgcn_mfma_f32_16x16x32_f16(af[c], ones, s1, 0, 0, 0);
        }
        f32x4 y0 = a0 + a1, y1 = b0 + b1, rsum = s0 + s1;

        // per-lane epilogue: lane holds y[slot r][k0],y[slot r][k1] directly
        float S0 = 0.0f, S1 = 0.0f;
#pragma unroll
        for (int r = 0; r < 4; ++r) {
            float v0 = y0[r], v1 = y1[r];
            if (first) {
                const int w = (u + 3 - r) & 3;
                if (w == j) { v0 = 256.0f; v1 = 256.0f; }      // initial-state path
                else if (w > j) { v0 = 0.0f; v1 = 0.0f; }      // invalid span
            }
            S0 = fmaf(v0, E0[r], S0);
            S1 = fmaf(v1, E1[r], S1);
        }
        float e0 = S0 * scl, e1 = S1 * scl;   // scl precomputed last step
        if (g4 == 0) {
            ebuf[u * LDP + k0] = (_Float16)e0;
            ebuf[u * LDP + k1] = (_Float16)e1;
        }
        e_last0 = e0; e_last1 = e1; M_last = Mcur;

        // trail (off the store path): ls_j, output select, next normalizer
        float lsj = C + __logf(rsum[sp]);     // ls[j] = LSE(alpha_{j-1})
        if (j == len) out_r = lsj;
        float delta = lsj - ls_prev;
        ls_prev = lsj;
        float Mn = lsj + 2.0f * delta;        // predict ls_{j+1} + delta_{j+1}
        scl = __expf(Mcur - Mn);              // C_{j+1} = M_j = Mcur
        Mcur = Mn;

        // LDS visibility only; emission prefetch stays in flight (no vmcnt drain)
        asm volatile("s_waitcnt lgkmcnt(0)" ::: "memory");
        __builtin_amdgcn_s_barrier();
        __builtin_amdgcn_sched_barrier(0);
    };

#define IC(v) std::integral_constant<int, v>{}
#define BC(v) std::integral_constant<bool, v>{}
    step(0, IC(0), BC(true));
    step(1, IC(1), BC(true));
    step(2, IC(2), BC(true));
    step(3, IC(3), BC(true));
    for (int jj = 4; jj < CS; jj += 4) {
        step(jj + 0, IC(0), BC(false));
        step(jj + 1, IC(1), BC(false));
        step(jj + 2, IC(2), BC(false));
        step(jj + 3, IC(3), BC(false));
    }
#undef IC
#undef BC

    // ls[128] = M_127 + log(sum_k e_127)
    float s = (g4 == 0) ? (e_last0 + e_last1) : 0.0f;
#pragma unroll
    for (int o = 32; o; o >>= 1) s += __shfl_xor(s, o, 64);
    if (lane == 0) red[wv] = s;
    __syncthreads();
    if (tid == 0) {
        float tot = 0.0f;
#pragma unroll
        for (int i = 0; i < 8; ++i) tot += red[i];
        float ls_full = M_last + __logf(tot);
        if (len == CS) out_r = ls_full;
        out[b] = out_r;
    }
}

extern "C" void kernel_launch(void* const* d_in, const int* in_sizes, int n_in,
                              void* d_out, int out_size, void* d_ws, size_t ws_size,
                              hipStream_t stream) {
    const float* logits    = (const float*)d_in[0];
    const float* T         = (const float*)d_in[1];
    const float* ham       = (const float*)d_in[2];
    const float* tag_mask  = (const float*)d_in[3];
    const int*   text_mask = (const int*)d_in[4];
    float* out = (float*)d_out;

    _Float16* eT = (_Float16*)d_ws;  // CB*CK*CK f16 = 6.3 MB scratch
    int n4 = CB * CK * CK / 4;
    prep_eT_kernel<<<(n4 + 255) / 256, 256, 0, stream>>>(
        (const f32x4*)T, (const f32x4*)tag_mask, (half4*)eT, n4);
    crf_scan_kernel<<<CB, 512, 0, stream>>>(logits, ham, eT, tag_mask, text_mask, out);
}

// Round 5
// 176.590 us; speedup vs baseline: 1.3905x; 1.3905x over previous
//
#include <hip/hip_runtime.h>
#include <hip/hip_bf16.h>
#include <type_traits>

typedef __attribute__((ext_vector_type(8))) _Float16 half8;
typedef __attribute__((ext_vector_type(4))) _Float16 half4;
typedef __attribute__((ext_vector_type(4))) float f32x4;

constexpr int CB = 48, CS = 128, CW = 4, CK = 256;
constexpr int LDP = 264;  // padded ebuf row stride (halves)

// eT[b][k][kp] = exp(T[b][k][kp] * tag_mask[b][k][kp]) as f16, float4-vectorized
__global__ void prep_eT_kernel(const f32x4* __restrict__ T,
                               const f32x4* __restrict__ tm,
                               half4* __restrict__ eT, int n4) {
    int i = blockIdx.x * 256 + threadIdx.x;
    if (i < n4) {
        f32x4 t = T[i], m = tm[i];
        half4 o;
        o[0] = (_Float16)__expf(t[0] * m[0]);
        o[1] = (_Float16)__expf(t[1] * m[1]);
        o[2] = (_Float16)__expf(t[2] * m[2]);
        o[3] = (_Float16)__expf(t[3] * m[3]);
        eT[i] = o;
    }
}

// 4 waves / 256 threads (the measured-best structure), wave wv owns k-slice [wv*64, wv*64+64).
// Round-3 grafts: all-ones-MFMA row sums (no shfl chain) + deferred normalizer (no log/exp
// on the store path). No register pins (they forced v-class spills); bfr may live in AGPRs.
__global__ __launch_bounds__(256, 1)
void crf_scan_kernel(const float* __restrict__ logits,
                     const float* __restrict__ ham,
                     const _Float16* __restrict__ eT,
                     const float* __restrict__ tag_mask,
                     const int* __restrict__ text_mask,
                     float* __restrict__ out) {
    const int b = blockIdx.x;
    const int tid = (int)threadIdx.x;
    const int wv = tid >> 6;
    const int lane = tid & 63;
    const int l16 = lane & 15;
    const int g4 = lane >> 4;

    __shared__ alignas(16) _Float16 ebuf[4 * LDP];  // ring: slot of alpha_i = i&3
    __shared__ float red[4];
    __shared__ int len_s;

    if (tid == 0) len_s = 0;
    __syncthreads();
    if (tid < CS) atomicAdd(&len_s, text_mask[b * CS + tid]);
    // alpha_{-1} = zeros row: e = exp(0-0) = 1 in slot 3, M_{-1} = 0
    ebuf[3 * LDP + tid] = (_Float16)1.0f;

    const float tm0 = tag_mask[(size_t)b * CK * CK + tid];  // tag_mask[b,0,k]

    // persistent eT B-fragments (AGPR/VGPR-resident for all 128 steps)
    half8 bfr[8][4];
    const _Float16* eTb = eT + (size_t)b * CK * CK;
#pragma unroll
    for (int c = 0; c < 8; ++c)
#pragma unroll
        for (int t = 0; t < 4; ++t) {
            int k = wv * 64 + t * 16 + l16;
            bfr[c][t] = *(const half8*)(eTb + (size_t)k * CK + c * 32 + g4 * 8);
        }

    const float* lgb = logits + (size_t)b * CS * CW * CK;
    const float* hcb = ham    + (size_t)b * CS * CW * CK;

    // persistent A-fragments, slot-duplicated rows: A row r holds slot (r&3).
    // => D register index r corresponds to slot r in EVERY lane (row=g4*4+r, (g4*4+r)&3==r)
    half8 af[8];
    {
        const _Float16 iv = ((l16 & 3) == 3) ? (_Float16)1.0f : (_Float16)0.0f;
        half8 v;
#pragma unroll
        for (int i = 0; i < 8; ++i) v[i] = iv;
#pragma unroll
        for (int c = 0; c < 8; ++c) af[c] = v;
    }

    // wave-uniform scan state
    float mr[4] = {0.0f, 0.0f, 0.0f, 0.0f};  // mr[s] = normalizer M of alpha in slot s
    float ls_prev = __logf(256.0f) - 2.0f;   // pretend ls_{-1}
    float out_r = __logf(256.0f);            // ls[0] (len==0 case)
    float e_last = 0.0f, M_last = 0.0f;
    // deferred normalizer: Mcur/scl for step j are decided at step j-1.
    float Mcur = __logf(256.0f) + 2.0f;      // M_0 = log256 + 2
    float scl  = __expf(0.0f - Mcur);        // C_0 = mr[3] = 0

    // 4-deep emission prefetch: set s holds step with j&3==s
    float lgp[4][4], hcp[4][4];
#pragma unroll
    for (int s = 0; s < 4; ++s)
#pragma unroll
        for (int w = 0; w < 4; ++w) {
            int idx = s * (CW * CK) + w * CK + tid;
            lgp[s][w] = lgb[idx];
            hcp[s][w] = hcb[idx];
        }

    __syncthreads();
    const int len = len_s;

    half8 ones;
#pragma unroll
    for (int i = 0; i < 8; ++i) ones[i] = (_Float16)1.0f;

    auto step = [&](int j, auto uc, auto firstc) {
        constexpr int u = uc.value;          // j & 3 (slot written this step)
        constexpr bool first = firstc.value; // j < 4 block
        constexpr int sp = (u + 3) & 3;      // slot of alpha_{j-1}

        // masked A-frag update: only row group sp changed since last step (16/64 lanes,
        // broadcast addresses within each group -> conflict-free)
        if ((l16 & 3) == sp) {
#pragma unroll
            for (int c = 0; c < 8; ++c)
                af[c] = *(const half8*)(ebuf + sp * LDP + c * 32 + g4 * 8);
        }

        // consume prefetch set u (issued 4 steps ago)
        float em_w[4];
#pragma unroll
        for (int w = 0; w < 4; ++w)
            em_w[w] = (lgp[u][w] + hcp[u][w]) * tm0;

        // reissue set u for step j+4 (stays in flight across raw barriers)
        {
            int jn = (j + 4 < CS) ? j + 4 : 0;  // wave-uniform clamp (dummy ok)
#pragma unroll
            for (int w = 0; w < 4; ++w) {
                int idx = jn * (CW * CK) + w * CK + tid;
                lgp[u][w] = lgb[idx];
                hcp[u][w] = hcb[idx];
            }
        }

        // slot weights need only mr[]/C (known since last step) -> off the MFMA path
        const float C = mr[sp];
        float E[4];
#pragma unroll
        for (int r = 0; r < 4; ++r)
            E[r] = __expf(mr[r] + em_w[(u + 3 - r) & 3] - C);
        mr[u] = Mcur;   // record this step's normalizer (after E read old mr[u])

        // MFMA: y[slot r][k] for 4 k-tiles + all-ones tile for row sums
        f32x4 acc[4];
#pragma unroll
        for (int t = 0; t < 4; ++t) acc[t] = (f32x4){0.0f, 0.0f, 0.0f, 0.0f};
        f32x4 s0 = {0, 0, 0, 0}, s1 = {0, 0, 0, 0};
#pragma unroll
        for (int c = 0; c < 8; ++c) {
#pragma unroll
            for (int t = 0; t < 4; ++t)
                acc[t] = __builtin_amdgcn_mfma_f32_16x16x32_f16(af[c], bfr[c][t], acc[t], 0, 0, 0);
            if (c & 1) s1 = __builtin_amdgcn_mfma_f32_16x16x32_f16(af[c], ones, s1, 0, 0, 0);
            else       s0 = __builtin_amdgcn_mfma_f32_16x16x32_f16(af[c], ones, s0, 0, 0, 0);
        }
        f32x4 rsum = s0 + s1;   // rsum[r] = rowsum of slot r (wave-uniform)

        // transpose-free epilogue: lane's k = tid lives in tile t = g4, reg r = slot r
        float S = 0.0f;
#pragma unroll
        for (int r = 0; r < 4; ++r) {
            float v01 = (g4 & 1) ? acc[1][r] : acc[0][r];
            float v23 = (g4 & 1) ? acc[3][r] : acc[2][r];
            float yv  = (g4 & 2) ? v23 : v01;
            if (first) {
                const int w = (u + 3 - r) & 3;   // width feeding slot r this step
                if (w == j) yv = 256.0f;         // initial-state path (alpha_{-1}=0 over K)
                else if (w > j) yv = 0.0f;       // invalid span
            }
            S = fmaf(yv, E[r], S);
        }
        float e = S * scl;                       // scl precomputed last step
        ebuf[u * LDP + tid] = (_Float16)e;
        e_last = e;
        M_last = Mcur;

        // trail (off the store path): ls_j, output select, next normalizer
        float lsj = C + __logf(rsum[sp]);        // ls[j] = LSE(alpha_{j-1})
        if (j == len) out_r = lsj;
        float delta = lsj - ls_prev;
        ls_prev = lsj;
        float Mn = lsj + 2.0f * delta;           // predict ls_{j+1} + delta_{j+1}
        scl = __expf(Mcur - Mn);                 // C_{j+1} = M_j = Mcur
        Mcur = Mn;

        // LDS visibility only; emission prefetch stays in flight (no vmcnt drain)
        asm volatile("s_waitcnt lgkmcnt(0)" ::: "memory");
        __builtin_amdgcn_s_barrier();
        __builtin_amdgcn_sched_barrier(0);
    };

#define IC(v) std::integral_constant<int, v>{}
#define BC(v) std::integral_constant<bool, v>{}
    step(0, IC(0), BC(true));
    step(1, IC(1), BC(true));
    step(2, IC(2), BC(true));
    step(3, IC(3), BC(true));
    for (int jj = 4; jj < CS; jj += 4) {
        step(jj + 0, IC(0), BC(false));
        step(jj + 1, IC(1), BC(false));
        step(jj + 2, IC(2), BC(false));
        step(jj + 3, IC(3), BC(false));
    }
#undef IC
#undef BC

    // ls[128] = M_127 + log(sum_k e_127)
    float s = e_last;
#pragma unroll
    for (int o = 32; o; o >>= 1) s += __shfl_xor(s, o, 64);
    if (lane == 0) red[wv] = s;
    __syncthreads();
    if (tid == 0) {
        float tot = red[0] + red[1] + red[2] + red[3];
        float ls_full = M_last + __logf(tot);
        if (len == CS) out_r = ls_full;
        out[b] = out_r;
    }
}

extern "C" void kernel_launch(void* const* d_in, const int* in_sizes, int n_in,
                              void* d_out, int out_size, void* d_ws, size_t ws_size,
                              hipStream_t stream) {
    const float* logits    = (const float*)d_in[0];
    const float* T         = (const float*)d_in[1];
    const float* ham       = (const float*)d_in[2];
    const float* tag_mask  = (const float*)d_in[3];
    const int*   text_mask = (const int*)d_in[4];
    float* out = (float*)d_out;

    _Float16* eT = (_Float16*)d_ws;  // CB*CK*CK f16 = 6.3 MB scratch
    int n4 = CB * CK * CK / 4;
    prep_eT_kernel<<<(n4 + 255) / 256, 256, 0, stream>>>(
        (const f32x4*)T, (const f32x4*)tag_mask, (half4*)eT, n4);
    crf_scan_kernel<<<CB, 256, 0, stream>>>(logits, ham, eT, tag_mask, text_mask, out);
}